// Round 13
// baseline (245.638 us; speedup 1.0000x reference)
//
#include <hip/hip_runtime.h>

#define NB 128
#define NS 100
#define NPRED 24
#define NHID 256
#define NSTEPS 16
#define NCTX 96
// R13: 400 blocks x 256 thr (4 waves), block = 32 rows. All-32x32x16 MFMA.
// psi(e,h) = (e&3)+8*(e>>2)+4h applied to ALL A/B images (bijective in (e,h)
// -> correct for any true HW k-map). D chains to next B via reg = e + 8*blk
// (derived from measured C/D map). Wave w owns hid chs [64w,64w+64).
// h1 exchange: LDS pair layout word[ch/2][row]. L3 k-split + f32 vred.
// Biases = unit-column MFMAs. W3 frags per-step from L2 (laundered).

typedef float f32x4 __attribute__((ext_vector_type(4)));
typedef float f32x16 __attribute__((ext_vector_type(16)));
typedef short bf16x8 __attribute__((ext_vector_type(8)));

__device__ __forceinline__ unsigned short f2bf(float f) {
    union { float f; unsigned u; } v; v.f = f;
    return (unsigned short)((v.u + 0x7fffu + ((v.u >> 16) & 1u)) >> 16);
}
// 1-op RNE pack. ONLY on VALU-produced values (never raw MFMA dst) [R11 lesson]
__device__ __forceinline__ unsigned cvtpk(float lo, float hi) {
    unsigned r;
    asm("v_cvt_pk_bf16_f32 %0, %1, %2" : "=v"(r) : "v"(lo), "v"(hi));
    return r;
}
__device__ __forceinline__ bf16x8 mk8(unsigned a, unsigned b, unsigned c, unsigned d) {
    union { unsigned u[4]; bf16x8 v; } x;
    x.u[0] = a; x.u[1] = b; x.u[2] = c; x.u[3] = d;
    return x.v;
}
__device__ __forceinline__ float lo16f(unsigned u) {
    union { unsigned u; float f; } c; c.u = u << 16; return c.f;
}
__device__ __forceinline__ float hi16f(unsigned u) {
    union { unsigned u; float f; } c; c.u = u & 0xffff0000u; return c.f;
}

// prep -> d_ws (ushorts): W1F [0,8192): 16 frags (tile*2+kblk), psi-imaged
//                         W3F [8192,16384): 16 frags (kblk)
//                         W2F [16384,81920): 128 frags (kblk*8+tile)
__global__ void prep_kernel(const float* __restrict__ W1,
                            const float* __restrict__ W2,
                            const float* __restrict__ W3,
                            unsigned short* __restrict__ wsf) {
    int i = blockIdx.x * 256 + threadIdx.x;   // 0..81919
    int pos = i & 511, l = pos >> 3, e = pos & 7;
    int psi = (e & 3) + 8 * (e >> 2) + 4 * (l >> 5);
    int m31 = l & 31;
    if (i < 8192) {
        int f = i >> 9;                // tile*2 + kblk
        int tile = f >> 1, kblk = f & 1;
        int k = kblk * 16 + psi;
        int m = tile * 32 + m31;
        wsf[i] = (k <= 24) ? f2bf(W1[k * NHID + m]) : (unsigned short)0;
    } else if (i < 16384) {
        int f = (i - 8192) >> 9;       // kblk
        int k = f * 16 + psi;
        wsf[i] = (m31 < NPRED) ? f2bf(W3[k * NPRED + m31]) : (unsigned short)0;
    } else {
        int f = (i - 16384) >> 9;      // kblk*8 + tile
        int kblk = f >> 3, tile = f & 7;
        int k = kblk * 16 + psi;
        int m = tile * 32 + m31;
        wsf[i] = f2bf(W2[k * NHID + m]);
    }
}

__global__ __launch_bounds__(256, 2) void fm_kernel(
    const float* __restrict__ past_target,
    const float* __restrict__ z0g,
    const float* __restrict__ W1, const float* __restrict__ b1,
    const float* __restrict__ b2, const float* __restrict__ b3,
    const unsigned short* __restrict__ wsf,
    float* __restrict__ out) {
    __shared__ __attribute__((aligned(16))) unsigned cbF[4096]; // 16 KB pairs
    __shared__ __attribute__((aligned(16))) unsigned exA[4096]; // 16 KB h1
    __shared__ __attribute__((aligned(16))) float vred[4096];   // 16 KB v
    __shared__ float locS[32];

    const int tid = threadIdx.x;
    const int g = blockIdx.x;        // 0..399; rows [g*32, g*32+32)

    // ---- prologue: fp32 cbias -> bf16 pair-words cbF[ch/2][row] ----
    {
        const int r = tid >> 3, c = tid & 7;   // row 0..31, 32-ch chunk 0..7
        const int bb = (g * 32 + r) & 127;
        const float* ctxp = past_target + bb * NCTX;
        float asum = 0.f;
        for (int k = 0; k < NCTX; k++) asum += fabsf(ctxp[k]);
        float loc = fmaxf(asum * (1.f / (float)NCTX), 1e-6f);
        if (c == 0) locS[r] = loc;
        float inv = 1.f / loc;
        f32x4 acc[8];
        const float* b1p = b1 + 32 * c;
#pragma unroll
        for (int u = 0; u < 8; u++) acc[u] = *(const f32x4*)(b1p + 4 * u);
        for (int k = 0; k < NCTX; k++) {
            float sx = ctxp[k] * inv;
            const f32x4* wr = (const f32x4*)(W1 + (26 + k) * NHID + 32 * c);
#pragma unroll
            for (int u = 0; u < 8; u++) {
                f32x4 wv = wr[u];
                acc[u].x += sx * wv.x; acc[u].y += sx * wv.y;
                acc[u].z += sx * wv.z; acc[u].w += sx * wv.w;
            }
        }
#pragma unroll
        for (int u = 0; u < 8; u++) {
            cbF[(16 * c + 2 * u) * 32 + r]     = cvtpk(acc[u].x, acc[u].y);
            cbF[(16 * c + 2 * u + 1) * 32 + r] = cvtpk(acc[u].z, acc[u].w);
        }
    }

    const int w = tid >> 6;          // wave: owns hid chs [64w, 64w+64)
    const int l = tid & 63;
    const int h = l >> 5, r = l & 31;
    const int l8 = l * 8;
    const int R = g * 32 + r;
    const int s = R >> 7, b = R & 127;

    // ---- persistent weight fragments ----
    bf16x8 w1r[4];                   // (tile 2w+(j>>1), kblk j&1)
#pragma unroll
    for (int j = 0; j < 4; j++)
        w1r[j] = *(const bf16x8*)(wsf + (4 * w + j) * 512 + l8);
    bf16x8 w2r[32];                  // [2*kblk + tt]
#pragma unroll
    for (int kb = 0; kb < 16; kb++)
#pragma unroll
        for (int tt = 0; tt < 2; tt++)
            w2r[2 * kb + tt] = *(const bf16x8*)(wsf + 16384 + (kb * 8 + 2 * w + tt) * 512 + l8);

    // bias unit-column frag pieces (value at psi==0 <=> e==0, h==0)
    unsigned b2w[2];
#pragma unroll
    for (int tt = 0; tt < 2; tt++)
        b2w[tt] = (l < 32) ? (unsigned)f2bf(b2[32 * (2 * w + tt) + r]) : 0u;
    unsigned b3w = (l < 32 && r < NPRED) ? (unsigned)f2bf(b3[r]) : 0u;
    const unsigned onew = (l < 32) ? 0x3f80u : 0u;   // bf16 1.0 at k-slot 0

    // ---- z state in 32x32 C'/D layout: zr[reg] = z[rho(l,reg)], rho=(reg&3)+8*(reg>>2)+4h
    float zr[16];
#pragma unroll
    for (int i = 0; i < 16; i++) zr[i] = 0.f;
    {
        const float* zrow = z0g + R * NPRED;
#pragma unroll
        for (int i = 0; i < 12; i += 2) {
            int rho = (i & 3) + 8 * (i >> 2) + 4 * h;   // even, <=22
            float2 t2 = *(const float2*)(zrow + rho);
            zr[i] = t2.x; zr[i + 1] = t2.y;
        }
    }

    __syncthreads();   // cbF + locS ready

    // cbias C'-pairs -> persistent packed regs (16)
    unsigned cbp[16];
#pragma unroll
    for (int tt = 0; tt < 2; tt++)
#pragma unroll
        for (int idx = 0; idx < 8; idx++)
            cbp[tt * 8 + idx] =
                cbF[(16 * (2 * w + tt) + 2 * h) * 32 + r + ((idx & 1) + 4 * (idx >> 1)) * 32];

    const float dt = 1.f / (float)NSTEPS;
#pragma unroll 1
    for (int step = 0; step < NSTEPS; step++) {
        // W3 frags for own kblks 4w..4w+3 (L2-resident; launder vs LICM)
        const unsigned short* w3p = wsf + 8192 + (4 * w) * 512 + l8;
        asm volatile("" : "+v"(w3p));
        bf16x8 w3f0 = *(const bf16x8*)(w3p);
        bf16x8 w3f1 = *(const bf16x8*)(w3p + 512);
        bf16x8 w3f2 = *(const bf16x8*)(w3p + 1024);
        bf16x8 w3f3 = *(const bf16x8*)(w3p + 1536);

        float t = 1.f - (float)step * dt;
        // bz frags: word j of blk = (zr[2j+8b], zr[2j+8b+1]); slot reg12 = t (h==0)
        bf16x8 bz0 = mk8(cvtpk(zr[0], zr[1]), cvtpk(zr[2], zr[3]),
                         cvtpk(zr[4], zr[5]), cvtpk(zr[6], zr[7]));
        bf16x8 bz1 = mk8(cvtpk(zr[8], zr[9]), cvtpk(zr[10], zr[11]),
                         cvtpk(h == 0 ? t : 0.f, zr[13]), cvtpk(zr[14], zr[15]));

        // ---- layer 1: per tile 2 MFMA; h1 -> exA pair words ----
#pragma unroll
        for (int tt = 0; tt < 2; tt++) {
            f32x16 acc;
#pragma unroll
            for (int idx = 0; idx < 8; idx++) {
                unsigned u = cbp[tt * 8 + idx];
                acc[2 * idx] = lo16f(u);
                acc[2 * idx + 1] = hi16f(u);
            }
            acc = __builtin_amdgcn_mfma_f32_32x32x16_bf16(w1r[2 * tt], bz0, acc, 0, 0, 0);
            acc = __builtin_amdgcn_mfma_f32_32x32x16_bf16(w1r[2 * tt + 1], bz1, acc, 0, 0, 0);
#pragma unroll
            for (int i = 0; i < 16; i++) acc[i] = fmaxf(acc[i], 0.f);
            int base = (16 * (2 * w + tt) + 2 * h) * 32 + r;
#pragma unroll
            for (int idx = 0; idx < 8; idx++)
                exA[base + ((idx & 1) + 4 * (idx >> 1)) * 32] = cvtpk(acc[2 * idx], acc[2 * idx + 1]);
        }
        __syncthreads();   // bar1: h1 exchanged

        // ---- layer 2: 16 kblks x 2 tiles = 32 MFMA + 2 bias MFMA ----
        f32x16 aA, aB;
#pragma unroll
        for (int i = 0; i < 16; i++) { aA[i] = 0.f; aB[i] = 0.f; }
#pragma unroll
        for (int kb = 0; kb < 16; kb++) {
            int pb = (8 * kb + 2 * h) * 32 + r;
            bf16x8 bb = mk8(exA[pb], exA[pb + 32], exA[pb + 128], exA[pb + 160]);
            aA = __builtin_amdgcn_mfma_f32_32x32x16_bf16(w2r[2 * kb], bb, aA, 0, 0, 0);
            aB = __builtin_amdgcn_mfma_f32_32x32x16_bf16(w2r[2 * kb + 1], bb, aB, 0, 0, 0);
        }
        bf16x8 bbU = mk8(onew, 0u, 0u, 0u);
        aA = __builtin_amdgcn_mfma_f32_32x32x16_bf16(mk8(b2w[0], 0u, 0u, 0u), bbU, aA, 0, 0, 0);
        aB = __builtin_amdgcn_mfma_f32_32x32x16_bf16(mk8(b2w[1], 0u, 0u, 0u), bbU, aB, 0, 0, 0);
#pragma unroll
        for (int i = 0; i < 16; i++) { aA[i] = fmaxf(aA[i], 0.f); aB[i] = fmaxf(aB[i], 0.f); }

        // ---- layer 3: own kblks (4w+2tt+bk); B from h2 regs (reg = e+8*bk) ----
        f32x16 v;
#pragma unroll
        for (int i = 0; i < 16; i++) v[i] = 0.f;
        {
            bf16x8 bA0 = mk8(cvtpk(aA[0], aA[1]), cvtpk(aA[2], aA[3]),
                             cvtpk(aA[4], aA[5]), cvtpk(aA[6], aA[7]));
            bf16x8 bA1 = mk8(cvtpk(aA[8], aA[9]), cvtpk(aA[10], aA[11]),
                             cvtpk(aA[12], aA[13]), cvtpk(aA[14], aA[15]));
            bf16x8 bB0 = mk8(cvtpk(aB[0], aB[1]), cvtpk(aB[2], aB[3]),
                             cvtpk(aB[4], aB[5]), cvtpk(aB[6], aB[7]));
            bf16x8 bB1 = mk8(cvtpk(aB[8], aB[9]), cvtpk(aB[10], aB[11]),
                             cvtpk(aB[12], aB[13]), cvtpk(aB[14], aB[15]));
            v = __builtin_amdgcn_mfma_f32_32x32x16_bf16(w3f0, bA0, v, 0, 0, 0);
            v = __builtin_amdgcn_mfma_f32_32x32x16_bf16(w3f1, bA1, v, 0, 0, 0);
            v = __builtin_amdgcn_mfma_f32_32x32x16_bf16(w3f2, bB0, v, 0, 0, 0);
            v = __builtin_amdgcn_mfma_f32_32x32x16_bf16(w3f3, bB1, v, 0, 0, 0);
            if (w == 0)  // b3 exactly once across the 4 partials
                v = __builtin_amdgcn_mfma_f32_32x32x16_bf16(mk8(b3w, 0u, 0u, 0u), bbU, v, 0, 0, 0);
        }
        // f32 partial exchange (plain ds_write of MFMA dst: hazard-safe, proven)
        {
            int vb = w * 1024 + l;
#pragma unroll
            for (int reg = 0; reg < 16; reg++) vred[vb + reg * 64] = v[reg];
        }
        __syncthreads();   // bar2: partials ready

        // ---- fixed-order all-reduce + Euler ----
        float sv[16];
#pragma unroll
        for (int i = 0; i < 16; i++) sv[i] = 0.f;
#pragma unroll
        for (int w2 = 0; w2 < 4; w2++)
#pragma unroll
            for (int reg = 0; reg < 16; reg++)
                sv[reg] += vred[w2 * 1024 + reg * 64 + l];
#pragma unroll
        for (int reg = 0; reg < 16; reg++) zr[reg] -= dt * sv[reg];
        // pads stay 0: W3 rows >=24 zero, b3 frag zero there.
        // exA rewrite next step safe: all readers finished before bar2.
        // vred rewrite next step safe: happens after next bar1.
    }

    // ---- store (wave 0; all waves hold identical z) ----
    if (w == 0) {
        float loc = locS[r];
        float* op = out + b * (NS * NPRED) + s * NPRED;
#pragma unroll
        for (int i = 0; i < 12; i += 2) {
            int rho = (i & 3) + 8 * (i >> 2) + 4 * h;
            float2 o; o.x = zr[i] * loc; o.y = zr[i + 1] * loc;
            *(float2*)(op + rho) = o;
        }
    }
}

extern "C" void kernel_launch(void* const* d_in, const int* in_sizes, int n_in,
                              void* d_out, int out_size, void* d_ws, size_t ws_size,
                              hipStream_t stream) {
    const float* past_target = (const float*)d_in[0];
    // d_in[1] past_observed_values: not used by the reference math
    const float* z0 = (const float*)d_in[2];
    const float* W1 = (const float*)d_in[3];
    const float* b1 = (const float*)d_in[4];
    const float* W2 = (const float*)d_in[5];
    const float* b2 = (const float*)d_in[6];
    const float* W3 = (const float*)d_in[7];
    const float* b3 = (const float*)d_in[8];

    unsigned short* wsf = (unsigned short*)d_ws;   // 160 KB frag image

    prep_kernel<<<320, 256, 0, stream>>>(W1, W2, W3, wsf);
    fm_kernel<<<400, 256, 0, stream>>>(past_target, z0, W1, b1, b2, b3,
                                       wsf, (float*)d_out);
}

// Round 14
// 134.690 us; speedup vs baseline: 1.8237x; 1.8237x over previous
//
#include <hip/hip_runtime.h>

#define NB 128
#define NS 100
#define NPRED 24
#define NHID 256
#define NSTEPS 16
#define NCTX 96
// R14 = R12 skeleton (127us proven) + register-pressure relief:
//  - w3 frags loaded per-step (early, laundered, L2-resident) not persistent
//  - b2/b3 packed bf16 persistent (b3 pre-scaled by dt)
//  - vred exchange packed bf16 (dt-scaled via compiler VALU before cvtpk --
//    never cvtpk a raw MFMA dst [R11 lesson])
// Goal: ~28 freed regs -> compiler prefetches exA ds_reads across k-chunks.

typedef float f32x4 __attribute__((ext_vector_type(4)));
typedef short bf16x8 __attribute__((ext_vector_type(8)));

__device__ __forceinline__ unsigned short f2bf(float f) {
    union { float f; unsigned u; } v; v.f = f;
    return (unsigned short)((v.u + 0x7fffu + ((v.u >> 16) & 1u)) >> 16);
}
// 1-op RNE pack. ONLY on VALU-produced values (never raw MFMA dst).
__device__ __forceinline__ unsigned cvtpk(float lo, float hi) {
    unsigned r;
    asm("v_cvt_pk_bf16_f32 %0, %1, %2" : "=v"(r) : "v"(lo), "v"(hi));
    return r;
}
__device__ __forceinline__ bf16x8 mk8(unsigned a, unsigned b, unsigned c, unsigned d) {
    union { unsigned u[4]; bf16x8 v; } x;
    x.u[0] = a; x.u[1] = b; x.u[2] = c; x.u[3] = d;
    return x.v;
}
__device__ __forceinline__ f32x4 bf4_to_f32x4(const unsigned short* pA) {
    uint2 uu = *(const uint2*)pA;
    union { unsigned u; float f; } c0, c1, c2, c3;
    c0.u = uu.x << 16; c1.u = uu.x & 0xffff0000u;
    c2.u = uu.y << 16; c3.u = uu.y & 0xffff0000u;
    f32x4 r; r.x = c0.f; r.y = c1.f; r.z = c2.f; r.w = c3.f;
    return r;
}
__device__ __forceinline__ f32x4 up4(unsigned a, unsigned b) {
    union { unsigned u; float f; } c0, c1, c2, c3;
    c0.u = a << 16; c1.u = a & 0xffff0000u;
    c2.u = b << 16; c3.u = b & 0xffff0000u;
    f32x4 r; r.x = c0.f; r.y = c1.f; r.z = c2.f; r.w = c3.f;
    return r;
}
__device__ __forceinline__ f32x4 relu4(f32x4 a) {
    a.x = fmaxf(a.x, 0.f); a.y = fmaxf(a.y, 0.f);
    a.z = fmaxf(a.z, 0.f); a.w = fmaxf(a.w, 0.f);
    return a;
}

// k-slot permutation within a 32-wide k-block at (lane l, elem e):
//   k_local = 16*(e>>2) + 4*(l>>4) + (e&3)
// Applied identically to A and B fragments (numerically verified R2-R12).

// prep -> d_ws (ushorts): W1F [0,8192) | W3F [8192,16384) | W2F [16384,81920)
__global__ void prep_kernel(const float* __restrict__ W1,
                            const float* __restrict__ W2,
                            const float* __restrict__ W3,
                            unsigned short* __restrict__ wsf) {
    int i = blockIdx.x * 256 + threadIdx.x;   // 0..81919
    if (i < 8192) {
        int T = i >> 9, ll = (i >> 3) & 63, e = i & 7;
        int k = 16 * (e >> 2) + 4 * (ll >> 4) + (e & 3);
        int m = 16 * T + (ll & 15);
        wsf[i] = (k <= 24) ? f2bf(W1[k * NHID + m]) : (unsigned short)0;
    } else if (i < 16384) {
        int idx = i - 8192;
        int ks = idx >> 10, T = (idx >> 9) & 1, ll = (idx >> 3) & 63, e = idx & 7;
        int k = 32 * ks + 16 * (e >> 2) + 4 * (ll >> 4) + (e & 3);
        int m = 16 * T + (ll & 15);
        wsf[i] = (m < NPRED) ? f2bf(W3[k * NPRED + m]) : (unsigned short)0;
    } else {
        int idx = i - 16384;
        int ks = idx >> 13, T = (idx >> 9) & 15, ll = (idx >> 3) & 63, e = idx & 7;
        int k = 32 * ks + 16 * (e >> 2) + 4 * (ll >> 4) + (e & 3);
        int m = 16 * T + (ll & 15);
        wsf[i] = f2bf(W2[k * NHID + m]);
    }
}

__global__ __launch_bounds__(256, 2) void fm_kernel(
    const float* __restrict__ past_target,
    const float* __restrict__ z0g,
    const float* __restrict__ W1, const float* __restrict__ b1,
    const float* __restrict__ b2, const float* __restrict__ b3,
    const unsigned short* __restrict__ wsf,
    float* __restrict__ out) {
    __shared__ __attribute__((aligned(16))) unsigned short cbF[4096]; // 8 KB
    __shared__ __attribute__((aligned(16))) unsigned exA[2048];       // 8 KB h1
    __shared__ __attribute__((aligned(16))) unsigned vpk[1024];       // 4 KB v

    const int tid = threadIdx.x;
    const int g = blockIdx.x;        // row-group 0..799

    // ---- one-time: fp32 cbias -> bf16 C-frags (16 rows x 16 ch-chunks) ----
    {
        const int r = tid >> 4, c = tid & 15;
        const int bb = (g * 16 + r) & 127;
        const float* ctxp = past_target + bb * NCTX;
        float asum = 0.f;
        for (int k = 0; k < NCTX; k++) asum += fabsf(ctxp[k]);
        float inv = 1.f / fmaxf(asum * (1.f / (float)NCTX), 1e-6f);
        f32x4 acc[4];
        const float* b1p = b1 + 16 * c;
#pragma unroll
        for (int u = 0; u < 4; u++) acc[u] = *(const f32x4*)(b1p + 4 * u);
        for (int k = 0; k < NCTX; k++) {
            float sx = ctxp[k] * inv;
            const f32x4* wr = (const f32x4*)(W1 + (26 + k) * NHID + 16 * c);
#pragma unroll
            for (int u = 0; u < 4; u++) {
                f32x4 w = wr[u];
                acc[u].x += sx * w.x; acc[u].y += sx * w.y;
                acc[u].z += sx * w.z; acc[u].w += sx * w.w;
            }
        }
        // C-frag layout: ch 16T+4qq+ii -> cbF[T*256 + qq*64 + r*4 + ii]
#pragma unroll
        for (int qq = 0; qq < 4; qq++) {
            int base = c * 256 + qq * 64 + r * 4;
            cbF[base + 0] = f2bf(acc[qq].x);
            cbF[base + 1] = f2bf(acc[qq].y);
            cbF[base + 2] = f2bf(acc[qq].z);
            cbF[base + 3] = f2bf(acc[qq].w);
        }
    }

    const int w = tid >> 6;          // wave 0..3: owns hidden ch [64w,64w+64)
    const int l = tid & 63;
    const int q = l >> 4, p = l & 15;
    const int R = g * 16 + p;
    const int s = R >> 7, b = R & 127;
    const int l8 = l * 8;

    // ---- persistent registers ----
    bf16x8 w1r[4];                   // W1 A-frags: 16 regs
    bf16x8 w2r[32];                  // W2 A-frags: 128 regs
#pragma unroll
    for (int j = 0; j < 4; j++)
        w1r[j] = *(const bf16x8*)(wsf + (4 * w + j) * 512 + l8);
#pragma unroll
    for (int ks = 0; ks < 8; ks++)
#pragma unroll
        for (int j = 0; j < 4; j++)
            w2r[ks * 4 + j] = *(const bf16x8*)(wsf + 16384 + (ks * 16 + 4 * w + j) * 512 + l8);

    // biases packed bf16 (saves 24 regs vs f32)
    unsigned b2p[8];
#pragma unroll
    for (int j = 0; j < 4; j++) {
        int ch = (4 * w + j) * 16 + 4 * q;
        b2p[2 * j]     = cvtpk(b2[ch], b2[ch + 1]);      // global loads = VALU-visible values
        b2p[2 * j + 1] = cvtpk(b2[ch + 2], b2[ch + 3]);
    }
    const float dt = 1.f / (float)NSTEPS;
    unsigned dtb3p[4];
    {
        f32x4 b3f0 = *(const f32x4*)(b3 + 4 * q);
        f32x4 b3f1 = {0.f, 0.f, 0.f, 0.f};
        if (q < 2) b3f1 = *(const f32x4*)(b3 + 16 + 4 * q);
        f32x4 d0 = b3f0 * dt, d1 = b3f1 * dt;
        dtb3p[0] = cvtpk(d0.x, d0.y); dtb3p[1] = cvtpk(d0.z, d0.w);
        dtb3p[2] = cvtpk(d1.x, d1.y); dtb3p[3] = cvtpk(d1.z, d1.w);
    }

    // ---- z state (replicated across the 4 waves; fixed-order math) ----
    f32x4 zs0, zs1;
    {
        const f32x4* zr = (const f32x4*)(z0g + R * NPRED);
        zs0 = zr[q];
        f32x4 zz = {0.f, 0.f, 0.f, 0.f};
        zs1 = zz;
        if (q < 2) zs1 = zr[4 + q];
    }

    __syncthreads();   // cbF ready

    f32x4 cbr[4];
#pragma unroll
    for (int j = 0; j < 4; j++)
        cbr[j] = bf4_to_f32x4(cbF + (4 * w + j) * 256 + q * 64 + p * 4);

#pragma unroll 1
    for (int step = 0; step < NSTEPS; step++) {
        // ---- early-issue W3 frags for own ks=2w,2w+1 (L2-resident; used in
        // layer 3 -> ~full step of latency cover). Laundered vs LICM. ----
        const unsigned short* w3p = wsf + 8192 + (2 * w) * 1024 + l8;
        asm volatile("" : "+v"(w3p));
        bf16x8 w3f0 = *(const bf16x8*)(w3p);
        bf16x8 w3f1 = *(const bf16x8*)(w3p + 512);
        bf16x8 w3f2 = *(const bf16x8*)(w3p + 1024);
        bf16x8 w3f3 = *(const bf16x8*)(w3p + 1536);

        float t = 1.f - (float)step * dt;
        float z10 = (q == 2) ? t : zs1.x;   // channel 24 carries t
        // zs/z10 are VALU-produced -> cvtpk safe
        bf16x8 bz = mk8(cvtpk(zs0.x, zs0.y), cvtpk(zs0.z, zs0.w),
                        cvtpk(z10, zs1.y), cvtpk(zs1.z, zs1.w));

        // ---- layer 1 (own 64 ch): 4 MFMA, all-register -> exA ----
#pragma unroll
        for (int j = 0; j < 4; j++) {
            f32x4 h = relu4(__builtin_amdgcn_mfma_f32_16x16x32_bf16(w1r[j], bz, cbr[j], 0, 0, 0));
            exA[(8 * w + 2 * j) * 64 + l]     = cvtpk(h.x, h.y);
            exA[(8 * w + 2 * j + 1) * 64 + l] = cvtpk(h.z, h.w);
        }
        __syncthreads();   // bar1: h1 exchange complete

        // ---- layer 2 (own 64 ch, K=256): 32 MFMA, weights in regs ----
        f32x4 a0 = {0.f, 0.f, 0.f, 0.f}, a1 = a0, a2 = a0, a3 = a0;
#pragma unroll
        for (int ks = 0; ks < 8; ks++) {
            bf16x8 bb = mk8(exA[(4 * ks) * 64 + l], exA[(4 * ks + 1) * 64 + l],
                            exA[(4 * ks + 2) * 64 + l], exA[(4 * ks + 3) * 64 + l]);
            a0 = __builtin_amdgcn_mfma_f32_16x16x32_bf16(w2r[ks * 4 + 0], bb, a0, 0, 0, 0);
            a1 = __builtin_amdgcn_mfma_f32_16x16x32_bf16(w2r[ks * 4 + 1], bb, a1, 0, 0, 0);
            a2 = __builtin_amdgcn_mfma_f32_16x16x32_bf16(w2r[ks * 4 + 2], bb, a2, 0, 0, 0);
            a3 = __builtin_amdgcn_mfma_f32_16x16x32_bf16(w2r[ks * 4 + 3], bb, a3, 0, 0, 0);
        }
        // bias + relu + pack own h2 (VALU outputs -> cvtpk safe)
        unsigned bh2[8];
        {
            f32x4 h0 = relu4(a0 + up4(b2p[0], b2p[1]));
            f32x4 h1 = relu4(a1 + up4(b2p[2], b2p[3]));
            f32x4 h2 = relu4(a2 + up4(b2p[4], b2p[5]));
            f32x4 h3 = relu4(a3 + up4(b2p[6], b2p[7]));
            bh2[0] = cvtpk(h0.x, h0.y); bh2[1] = cvtpk(h0.z, h0.w);
            bh2[2] = cvtpk(h1.x, h1.y); bh2[3] = cvtpk(h1.z, h1.w);
            bh2[4] = cvtpk(h2.x, h2.y); bh2[5] = cvtpk(h2.z, h2.w);
            bh2[6] = cvtpk(h3.x, h3.y); bh2[7] = cvtpk(h3.z, h3.w);
        }

        // ---- layer 3 partial (own k-chunks ks=2w,2w+1): 4 MFMA ----
        f32x4 v0 = {0.f, 0.f, 0.f, 0.f}, v1 = v0;
        {
            bf16x8 bbA = mk8(bh2[0], bh2[1], bh2[2], bh2[3]);
            bf16x8 bbB = mk8(bh2[4], bh2[5], bh2[6], bh2[7]);
            v0 = __builtin_amdgcn_mfma_f32_16x16x32_bf16(w3f0, bbA, v0, 0, 0, 0);
            v1 = __builtin_amdgcn_mfma_f32_16x16x32_bf16(w3f1, bbA, v1, 0, 0, 0);
            v0 = __builtin_amdgcn_mfma_f32_16x16x32_bf16(w3f2, bbB, v0, 0, 0, 0);
            v1 = __builtin_amdgcn_mfma_f32_16x16x32_bf16(w3f3, bbB, v1, 0, 0, 0);
        }
        // dt-scale via compiler VALU (hazard-safe on MFMA dst), THEN cvtpk.
        {
            f32x4 vd0 = v0 * dt, vd1 = v1 * dt;
            vpk[(4 * w + 0) * 64 + l] = cvtpk(vd0.x, vd0.y);
            vpk[(4 * w + 1) * 64 + l] = cvtpk(vd0.z, vd0.w);
            vpk[(4 * w + 2) * 64 + l] = cvtpk(vd1.x, vd1.y);
            vpk[(4 * w + 3) * 64 + l] = cvtpk(vd1.z, vd1.w);
        }
        __syncthreads();   // bar2: partials ready

        // ---- all-reduce in FIXED order (z identical across waves) ----
        f32x4 sv0 = {0.f, 0.f, 0.f, 0.f}, sv1 = sv0;
#pragma unroll
        for (int w2 = 0; w2 < 4; w2++) {
            f32x4 t0 = up4(vpk[(4 * w2 + 0) * 64 + l], vpk[(4 * w2 + 1) * 64 + l]);
            f32x4 t1 = up4(vpk[(4 * w2 + 2) * 64 + l], vpk[(4 * w2 + 3) * 64 + l]);
            sv0.x += t0.x; sv0.y += t0.y; sv0.z += t0.z; sv0.w += t0.w;
            sv1.x += t1.x; sv1.y += t1.y; sv1.z += t1.z; sv1.w += t1.w;
        }

        // ---- Euler: z -= (dt*v_sum + dt*b3) (pads: v==0, dtb3==0) ----
        {
            f32x4 d0 = up4(dtb3p[0], dtb3p[1]), d1 = up4(dtb3p[2], dtb3p[3]);
            zs0.x -= sv0.x + d0.x; zs0.y -= sv0.y + d0.y;
            zs0.z -= sv0.z + d0.z; zs0.w -= sv0.w + d0.w;
            zs1.x -= sv1.x + d1.x; zs1.y -= sv1.y + d1.y;
            zs1.z -= sv1.z + d1.z; zs1.w -= sv1.w + d1.w;
        }
        // no bar: next exA writes safe (readers done pre-bar2); next vpk
        // writes fenced by bar1 of next step.
    }

    // ---- store (wave 0 only; loc recomputed once) ----
    if (w == 0) {
        const float* ctxl = past_target + b * NCTX;
        float asum = 0.f;
        for (int k = 0; k < NCTX; k++) asum += fabsf(ctxl[k]);
        float loc = fmaxf(asum * (1.f / (float)NCTX), 1e-6f);
        float* op = out + b * (NS * NPRED) + s * NPRED;
        f32x4 o0 = zs0 * loc;
        *(f32x4*)(op + 4 * q) = o0;
        if (q < 2) { f32x4 o1 = zs1 * loc; *(f32x4*)(op + 16 + 4 * q) = o1; }
    }
}

extern "C" void kernel_launch(void* const* d_in, const int* in_sizes, int n_in,
                              void* d_out, int out_size, void* d_ws, size_t ws_size,
                              hipStream_t stream) {
    const float* past_target = (const float*)d_in[0];
    // d_in[1] past_observed_values: not used by the reference math
    const float* z0 = (const float*)d_in[2];
    const float* W1 = (const float*)d_in[3];
    const float* b1 = (const float*)d_in[4];
    const float* W2 = (const float*)d_in[5];
    const float* b2 = (const float*)d_in[6];
    const float* W3 = (const float*)d_in[7];
    const float* b3 = (const float*)d_in[8];

    unsigned short* wsf = (unsigned short*)d_ws;   // 160 KB frag image (proven)

    prep_kernel<<<320, 256, 0, stream>>>(W1, W2, W3, wsf);
    fm_kernel<<<800, 256, 0, stream>>>(past_target, z0, W1, b1, b2, b3,
                                       wsf, (float*)d_out);
}